// Round 1
// baseline (768.900 us; speedup 1.0000x reference)
//
#include <hip/hip_runtime.h>
#include <math.h>

#define V96 (96*96*96)

// ---------- helpers ----------

__device__ __forceinline__ int reflect_idx(int t, int n) {
  // numpy/jnp 'reflect' (no border repeat); p=2 so one fold suffices
  if (t < 0) t = -t;
  if (t >= n) t = 2 * n - 2 - t;
  return t;
}

__device__ __forceinline__ void cswap(float& a, float& b) {
  float lo = fminf(a, b);
  float hi = fmaxf(a, b);
  a = lo;
  b = hi;
}

// Exact median of v[0..124]; v[125..127] must be +inf.
// Batcher odd-even mergesort network, n=128 (loop-generated, fully unrolled,
// branchless). Only v[62] is consumed -> DCE prunes dead comparator halves.
__device__ __forceinline__ float median125(float (&v)[128]) {
  constexpr int n = 128;
#pragma unroll
  for (int p = 1; p < n; p <<= 1) {
#pragma unroll
    for (int k = p; k >= 1; k >>= 1) {
#pragma unroll
      for (int j = k % p; j <= n - 1 - k; j += 2 * k) {
#pragma unroll
        for (int i = 0; i < k; i++) {
          if (i + j + k <= n - 1) {
            if ((i + j) / (2 * p) == (i + j + k) / (2 * p)) {
              cswap(v[i + j], v[i + j + k]);
            }
          }
        }
      }
    }
  }
  return v[62];
}

// block = 256 threads, reduce a double to thread 0's return value
__device__ __forceinline__ double block_reduce_sum(double val, double* sh) {
  int tid = threadIdx.x + threadIdx.y * blockDim.x +
            threadIdx.z * blockDim.x * blockDim.y;
  int lane = tid & 63;
  int wv = tid >> 6;
#pragma unroll
  for (int off = 32; off > 0; off >>= 1) val += __shfl_down(val, off, 64);
  if (lane == 0) sh[wv] = val;
  __syncthreads();
  double r = 0.0;
  if (tid == 0) {
#pragma unroll
    for (int i = 0; i < 4; i++) r += sh[i];
  }
  return r;
}

// ---------- stage 1: masked fields ----------

__global__ __launch_bounds__(256) void prep_mask_kernel(
    const float* __restrict__ pred_b, const float* __restrict__ targets,
    float* __restrict__ bxm, float* __restrict__ bym) {
  int i = blockIdx.x * 256 + threadIdx.x;
  if (i >= V96) return;
  float bxp = pred_b[i];
  float byp = pred_b[V96 + i];
  float bxt = targets[i];
  float byt = targets[V96 + i];
  float m = (bxp * bxt + byp * byt > 0.0f) ? 1.0f : -1.0f;
  bxm[i] = bxt * m;
  bym[i] = byt * m;
}

// ---------- stage 2: div-c flux reduction (95^3 cells) ----------

__global__ __launch_bounds__(256) void div_kernel(
    const float* __restrict__ bx, const float* __restrict__ by,
    const float* __restrict__ bz, const float* __restrict__ z,
    double* __restrict__ acc_sum, double* __restrict__ acc_sq) {
  __shared__ double sh1[4];
  __shared__ double sh2[4];
  const int N = 95 * 95 * 95;
  int idx = blockIdx.x * 256 + threadIdx.x;
  double fs = 0.0, fq = 0.0;
  if (idx < N) {
    int w = idx % 95;
    int t = idx / 95;
    int h = t % 95;
    int d = t / 95;
    int o = (d * 96 + h) * 96 + w;
    // corner c(i,j,l) -> offset o + i*9216 + j*96 + l
#define LD8(A, p)                                                             \
  float A##000 = p[o], A##001 = p[o + 1], A##010 = p[o + 96],                 \
        A##011 = p[o + 97], A##100 = p[o + 9216], A##101 = p[o + 9217],       \
        A##110 = p[o + 9312], A##111 = p[o + 9313];
    LD8(bxv, bx)
    LD8(byv, by)
    LD8(bzv, bz)
    LD8(zv, z)
#undef LD8
    float az1 = fabsf(zv001 - zv000);  // |z[0,0,1]-z[0,0,0]|
    float az2 = fabsf(zv011 - zv010);  // |z[0,1,1]-z[0,1,0]|
    float az3 = fabsf(zv101 - zv100);  // |z[1,0,1]-z[1,0,0]|
    float az4 = fabsf(zv111 - zv110);  // |z[1,1,1]-z[1,1,0]|
    const float c6 = 1.0f / 6.0f;
    const float c3 = 1.0f / 3.0f;
    float flux =
        0.25f * (bxv100 + bxv110 + bxv101 + bxv111) * 0.5f * (az3 + az4) -
        0.25f * (bxv000 + bxv010 + bxv001 + bxv011) * 0.5f * (az1 + az2) +
        0.25f * (byv010 + byv110 + byv011 + byv111) * 0.5f * (az2 + az4) -
        0.25f * (byv000 + byv100 + byv001 + byv101) * 0.5f * (az1 + az3) +
        0.5f * ((bzv001 + bzv101 + bzv111) + (bzv001 + bzv111 + bzv011)) * c3 -
        0.5f * ((bzv000 + bzv100 + bzv110) + (bzv000 + bzv110 + bzv010)) * c3 +
        (bxv001 + bxv101 + bxv111) * (zv001 - zv101) * c6 +
        (bxv001 + bxv011 + bxv111) * (zv011 - zv111) * c6 +
        (byv001 + byv101 + byv111) * (zv101 - zv111) * c6 +
        (byv001 + byv011 + byv111) * (zv001 - zv011) * c6 -
        ((bxv000 + bxv100 + bxv110) * (zv000 - zv100) * c6 +
         (bxv000 + bxv010 + bxv110) * (zv010 - zv110) * c6 +
         (byv000 + byv100 + byv110) * (zv100 - zv110) * c6 +
         (byv000 + byv010 + byv110) * (zv000 - zv010) * c6);
    float sbx = bxv000 + bxv001 + bxv010 + bxv011 + bxv100 + bxv101 + bxv110 +
                bxv111;
    float sby = byv000 + byv001 + byv010 + byv011 + byv100 + byv101 + byv110 +
                byv111;
    float sbz = bzv000 + bzv001 + bzv010 + bzv011 + bzv100 + bzv101 + bzv110 +
                bzv111;
    float ave = 0.015625f * (sbx * sbx + sby * sby + sbz * sbz) + 1e-8f;
    float res = flux * flux;
    float flx1 = res * res / ave;
    fs = (double)flx1;
    fq = (double)flx1 * (double)flx1;
  }
  double bs = block_reduce_sum(fs, sh1);
  double bq = block_reduce_sum(fq, sh2);
  int tid = threadIdx.x;
  if (tid == 0) {
    atomicAdd(acc_sum, bs);
    atomicAdd(acc_sq, bq);
  }
}

// ---------- stage 3: median filter + sum((x-med)^2) ----------
// MODE 0: plain field f (dims D,H,W)
// MODE 1: jx on the fly (dims 96,95,95) from bzp,bym
// MODE 2: jy on the fly (dims 95,96,95) from bxm,bzp
// MODE 3: jz on the fly (dims 95,95,96) from bym,bxm

template <int MODE>
__global__ __launch_bounds__(256) void med_kernel(
    const float* __restrict__ f, const float* __restrict__ bxm,
    const float* __restrict__ bym, const float* __restrict__ bzp, int D, int H,
    int W, double* __restrict__ acc) {
  __shared__ float tile[8][8][20];
  __shared__ double sh[4];
  const int w0 = blockIdx.x * 16;
  const int h0 = blockIdx.y * 4;
  const int d0 = blockIdx.z * 4;
  const int tid = threadIdx.x + threadIdx.y * 16 + threadIdx.z * 64;

  for (int il = tid; il < 1280; il += 256) {
    int lw = il % 20;
    int lh = (il / 20) % 8;
    int ld = il / 160;
    int gw = reflect_idx(w0 + lw - 2, W);
    int gh = reflect_idx(h0 + lh - 2, H);
    int gd = reflect_idx(d0 + ld - 2, D);
    float val;
    if (MODE == 0) {
      val = f[(gd * H + gh) * W + gw];
    } else {
      int o = (gd * 96 + gh) * 96 + gw;
      if (MODE == 1) {
        // jx = 0.5*(Bz(d,h,w)-Bz(d,h+1,w)+Bz(d,h,w+1)-Bz(d,h+1,w+1))
        //     -0.5*(By(d,h,w)-By(d,h,w+1)+By(d,h+1,w)-By(d,h+1,w+1))
        val = 0.5f * ((bzp[o] - bzp[o + 96] + bzp[o + 1] - bzp[o + 97]) -
                      (bym[o] - bym[o + 1] + bym[o + 96] - bym[o + 97]));
      } else if (MODE == 2) {
        // jy = 0.5*(Bx(d,h,w)-Bx(d,h,w+1)+Bx(d+1,h,w)-Bx(d+1,h,w+1))
        //     -0.5*(Bz(d,h,w)-Bz(d+1,h,w)+Bz(d,h,w+1)-Bz(d+1,h,w+1))
        val = 0.5f *
              ((bxm[o] - bxm[o + 1] + bxm[o + 9216] - bxm[o + 9217]) -
               (bzp[o] - bzp[o + 9216] + bzp[o + 1] - bzp[o + 9217]));
      } else {
        // jz = 0.5*(By(d,h,w)-By(d+1,h,w)+By(d,h+1,w)-By(d+1,h+1,w))
        //     -0.5*(Bx(d,h,w)-Bx(d,h+1,w)+Bx(d+1,h,w)-Bx(d+1,h+1,w))
        val = 0.5f *
              ((bym[o] - bym[o + 9216] + bym[o + 96] - bym[o + 9312]) -
               (bxm[o] - bxm[o + 96] + bxm[o + 9216] - bxm[o + 9312]));
      }
    }
    tile[ld][lh][lw] = val;
  }
  __syncthreads();

  const int w = w0 + threadIdx.x;
  const int h = h0 + threadIdx.y;
  const int d = d0 + threadIdx.z;

  float v[128];
#pragma unroll
  for (int i = 0; i < 5; i++) {
#pragma unroll
    for (int j = 0; j < 5; j++) {
#pragma unroll
      for (int l = 0; l < 5; l++) {
        v[(i * 5 + j) * 5 + l] =
            tile[threadIdx.z + i][threadIdx.y + j][threadIdx.x + l];
      }
    }
  }
  float center = tile[threadIdx.z + 2][threadIdx.y + 2][threadIdx.x + 2];
  v[125] = __builtin_inff();
  v[126] = __builtin_inff();
  v[127] = __builtin_inff();
  float med = median125(v);
  float dlt = med - center;
  double c =
      (w < W && h < H && d < D) ? (double)dlt * (double)dlt : 0.0;
  double bs = block_reduce_sum(c, sh);
  if (tid == 0) atomicAdd(acc, bs);
}

// ---------- stage 4: finalize 6 scalars ----------

__global__ void finalize_kernel(const double* __restrict__ a,
                                float* __restrict__ out) {
  const double Nd = 95.0 * 95.0 * 95.0;      // 857375
  const double Nj = 96.0 * 95.0 * 95.0;      // 866400 (same for jx,jy,jz)
  const double Nv = 96.0 * 96.0 * 96.0;      // 884736
  double mp = a[0] / Nd;
  double mt = a[2] / Nd;
  out[0] = (float)mp;
  out[1] = (float)(a[1] / Nd - mp * mp);
  out[2] = (float)mt;
  out[3] = (float)(a[3] / Nd - mt * mt);
  out[4] = (float)((a[4] + a[5] + a[6]) / Nj);
  out[5] = (float)((a[7] + a[8] + a[9] + a[10]) / Nv);
}

// ---------- launcher ----------

extern "C" void kernel_launch(void* const* d_in, const int* in_sizes, int n_in,
                              void* d_out, int out_size, void* d_ws,
                              size_t ws_size, hipStream_t stream) {
  (void)in_sizes;
  (void)n_in;
  (void)out_size;
  (void)ws_size;
  const float* pred_b = (const float*)d_in[0];
  const float* pred_z = (const float*)d_in[1];
  const float* targets = (const float*)d_in[2];
  float* out = (float*)d_out;

  // ws layout: [0,256) accumulator doubles (11 used), then bxm, bym fields
  double* acc = (double*)d_ws;
  float* bxm = (float*)((char*)d_ws + 256);
  float* bym = bxm + V96;

  const float* bzt = targets + 2 * V96;
  const float* bzp = pred_b + 2 * V96;

  hipMemsetAsync(d_ws, 0, 256, stream);

  prep_mask_kernel<<<dim3((V96 + 255) / 256), dim3(256), 0, stream>>>(
      pred_b, targets, bxm, bym);

  const int nDiv = 95 * 95 * 95;
  div_kernel<<<dim3((nDiv + 255) / 256), dim3(256), 0, stream>>>(
      pred_b, pred_b + V96, bzt, pred_z, acc + 0, acc + 1);
  div_kernel<<<dim3((nDiv + 255) / 256), dim3(256), 0, stream>>>(
      bxm, bym, bzt, pred_z, acc + 2, acc + 3);

  dim3 blk(16, 4, 4);
  dim3 grd(6, 24, 24);  // ceil(96/16)=6, ceil(96/4)=24 (covers 95 dims too)
  med_kernel<1><<<grd, blk, 0, stream>>>(nullptr, bxm, bym, bzp, 96, 95, 95,
                                         acc + 4);
  med_kernel<2><<<grd, blk, 0, stream>>>(nullptr, bxm, bym, bzp, 95, 96, 95,
                                         acc + 5);
  med_kernel<3><<<grd, blk, 0, stream>>>(nullptr, bxm, bym, bzp, 95, 95, 96,
                                         acc + 6);
  med_kernel<0><<<grd, blk, 0, stream>>>(bxm, bxm, bym, bzp, 96, 96, 96,
                                         acc + 7);
  med_kernel<0><<<grd, blk, 0, stream>>>(bym, bxm, bym, bzp, 96, 96, 96,
                                         acc + 8);
  med_kernel<0><<<grd, blk, 0, stream>>>(pred_b, bxm, bym, bzp, 96, 96, 96,
                                         acc + 9);
  med_kernel<0><<<grd, blk, 0, stream>>>(pred_b + V96, bxm, bym, bzp, 96, 96,
                                         96, acc + 10);

  finalize_kernel<<<1, 1, 0, stream>>>(acc, out);
}

// Round 2
// 645.658 us; speedup vs baseline: 1.1909x; 1.1909x over previous
//
#include <hip/hip_runtime.h>
#include <math.h>

#define V96 (96*96*96)
#define NDIVBLK 3350   // ceil(95^3/256)
#define NMEDBLK 3456   // 6*24*24

// ws layout (doubles): [0..4*NDIVBLK) div partials (sum_p, sq_p, sum_t, sq_t
// interleaved per-array), then 7*NMEDBLK med partials, then float bxm, bym.

// ---------- helpers ----------

__device__ __forceinline__ int reflect_idx(int t, int n) {
  if (t < 0) t = -t;
  if (t >= n) t = 2 * n - 2 - t;
  return t;
}

__device__ __forceinline__ void cswap(float& a, float& b) {
  float lo = fminf(a, b);
  float hi = fmaxf(a, b);
  a = lo;
  b = hi;
}

// Exact median of v[0..124]; v[125..127] must be +inf.
// Batcher odd-even mergesort network, n=128, branchless; only v[62] is
// consumed -> DCE prunes dead comparator halves.
__device__ __forceinline__ float median125(float (&v)[128]) {
  constexpr int n = 128;
#pragma unroll
  for (int p = 1; p < n; p <<= 1) {
#pragma unroll
    for (int k = p; k >= 1; k >>= 1) {
#pragma unroll
      for (int j = k % p; j <= n - 1 - k; j += 2 * k) {
#pragma unroll
        for (int i = 0; i < k; i++) {
          if (i + j + k <= n - 1) {
            if ((i + j) / (2 * p) == (i + j + k) / (2 * p)) {
              cswap(v[i + j], v[i + j + k]);
            }
          }
        }
      }
    }
  }
  return v[62];
}

// 256-thread block: reduce val across block; result valid on tid 0.
__device__ __forceinline__ double block_reduce_sum(double val, double* sh) {
  int tid = threadIdx.x + threadIdx.y * blockDim.x +
            threadIdx.z * blockDim.x * blockDim.y;
  int lane = tid & 63;
  int wv = tid >> 6;
#pragma unroll
  for (int off = 32; off > 0; off >>= 1) val += __shfl_down(val, off, 64);
  if (lane == 0) sh[wv] = val;
  __syncthreads();
  double r = 0.0;
  if (tid == 0) {
#pragma unroll
    for (int i = 0; i < 4; i++) r += sh[i];
  }
  return r;
}

// ---------- stage 1: masked fields ----------

__global__ __launch_bounds__(256) void prep_mask_kernel(
    const float* __restrict__ pred_b, const float* __restrict__ targets,
    float* __restrict__ bxm, float* __restrict__ bym) {
  int i = blockIdx.x * 256 + threadIdx.x;
  if (i >= V96) return;
  float bxp = pred_b[i];
  float byp = pred_b[V96 + i];
  float bxt = targets[i];
  float byt = targets[V96 + i];
  float m = (bxp * bxt + byp * byt > 0.0f) ? 1.0f : -1.0f;
  bxm[i] = bxt * m;
  bym[i] = byt * m;
}

// ---------- stage 2: div-c flux reduction (95^3 cells) ----------

__global__ __launch_bounds__(256) void div_kernel(
    const float* __restrict__ bx, const float* __restrict__ by,
    const float* __restrict__ bz, const float* __restrict__ z,
    double* __restrict__ part_sum, double* __restrict__ part_sq) {
  __shared__ double sh1[4];
  __shared__ double sh2[4];
  const int N = 95 * 95 * 95;
  int idx = blockIdx.x * 256 + threadIdx.x;
  double fs = 0.0, fq = 0.0;
  if (idx < N) {
    int w = idx % 95;
    int t = idx / 95;
    int h = t % 95;
    int d = t / 95;
    int o = (d * 96 + h) * 96 + w;
#define LD8(A, p)                                                             \
  float A##000 = p[o], A##001 = p[o + 1], A##010 = p[o + 96],                 \
        A##011 = p[o + 97], A##100 = p[o + 9216], A##101 = p[o + 9217],       \
        A##110 = p[o + 9312], A##111 = p[o + 9313];
    LD8(bxv, bx)
    LD8(byv, by)
    LD8(bzv, bz)
    LD8(zv, z)
#undef LD8
    float az1 = fabsf(zv001 - zv000);
    float az2 = fabsf(zv011 - zv010);
    float az3 = fabsf(zv101 - zv100);
    float az4 = fabsf(zv111 - zv110);
    const float c6 = 1.0f / 6.0f;
    const float c3 = 1.0f / 3.0f;
    float flux =
        0.25f * (bxv100 + bxv110 + bxv101 + bxv111) * 0.5f * (az3 + az4) -
        0.25f * (bxv000 + bxv010 + bxv001 + bxv011) * 0.5f * (az1 + az2) +
        0.25f * (byv010 + byv110 + byv011 + byv111) * 0.5f * (az2 + az4) -
        0.25f * (byv000 + byv100 + byv001 + byv101) * 0.5f * (az1 + az3) +
        0.5f * ((bzv001 + bzv101 + bzv111) + (bzv001 + bzv111 + bzv011)) * c3 -
        0.5f * ((bzv000 + bzv100 + bzv110) + (bzv000 + bzv110 + bzv010)) * c3 +
        (bxv001 + bxv101 + bxv111) * (zv001 - zv101) * c6 +
        (bxv001 + bxv011 + bxv111) * (zv011 - zv111) * c6 +
        (byv001 + byv101 + byv111) * (zv101 - zv111) * c6 +
        (byv001 + byv011 + byv111) * (zv001 - zv011) * c6 -
        ((bxv000 + bxv100 + bxv110) * (zv000 - zv100) * c6 +
         (bxv000 + bxv010 + bxv110) * (zv010 - zv110) * c6 +
         (byv000 + byv100 + byv110) * (zv100 - zv110) * c6 +
         (byv000 + byv010 + byv110) * (zv000 - zv010) * c6);
    float sbx = bxv000 + bxv001 + bxv010 + bxv011 + bxv100 + bxv101 + bxv110 +
                bxv111;
    float sby = byv000 + byv001 + byv010 + byv011 + byv100 + byv101 + byv110 +
                byv111;
    float sbz = bzv000 + bzv001 + bzv010 + bzv011 + bzv100 + bzv101 + bzv110 +
                bzv111;
    float ave = 0.015625f * (sbx * sbx + sby * sby + sbz * sbz) + 1e-8f;
    float res = flux * flux;
    float flx1 = res * res / ave;
    fs = (double)flx1;
    fq = (double)flx1 * (double)flx1;
  }
  double bs = block_reduce_sum(fs, sh1);
  double bq = block_reduce_sum(fq, sh2);
  if (threadIdx.x == 0) {
    part_sum[blockIdx.x] = bs;
    part_sq[blockIdx.x] = bq;
  }
}

// ---------- stage 3: median filter + sum((x-med)^2) ----------
// MODE 0: plain field f (dims D,H,W)
// MODE 1: jx on the fly (96,95,95)   MODE 2: jy (95,96,95)   MODE 3: jz (95,95,96)

template <int MODE>
__global__ __launch_bounds__(256) void med_kernel(
    const float* __restrict__ f, const float* __restrict__ bxm,
    const float* __restrict__ bym, const float* __restrict__ bzp, int D, int H,
    int W, double* __restrict__ part) {
  __shared__ float tile[8][8][20];
  __shared__ double sh[4];
  const int w0 = blockIdx.x * 16;
  const int h0 = blockIdx.y * 4;
  const int d0 = blockIdx.z * 4;
  const int tid = threadIdx.x + threadIdx.y * 16 + threadIdx.z * 64;

  for (int il = tid; il < 1280; il += 256) {
    int lw = il % 20;
    int lh = (il / 20) % 8;
    int ld = il / 160;
    int gw = reflect_idx(w0 + lw - 2, W);
    int gh = reflect_idx(h0 + lh - 2, H);
    int gd = reflect_idx(d0 + ld - 2, D);
    float val;
    if (MODE == 0) {
      val = f[(gd * H + gh) * W + gw];
    } else {
      int o = (gd * 96 + gh) * 96 + gw;
      if (MODE == 1) {
        val = 0.5f * ((bzp[o] - bzp[o + 96] + bzp[o + 1] - bzp[o + 97]) -
                      (bym[o] - bym[o + 1] + bym[o + 96] - bym[o + 97]));
      } else if (MODE == 2) {
        val = 0.5f *
              ((bxm[o] - bxm[o + 1] + bxm[o + 9216] - bxm[o + 9217]) -
               (bzp[o] - bzp[o + 9216] + bzp[o + 1] - bzp[o + 9217]));
      } else {
        val = 0.5f *
              ((bym[o] - bym[o + 9216] + bym[o + 96] - bym[o + 9312]) -
               (bxm[o] - bxm[o + 96] + bxm[o + 9216] - bxm[o + 9312]));
      }
    }
    tile[ld][lh][lw] = val;
  }
  __syncthreads();

  const int w = w0 + threadIdx.x;
  const int h = h0 + threadIdx.y;
  const int d = d0 + threadIdx.z;

  float v[128];
#pragma unroll
  for (int i = 0; i < 5; i++) {
#pragma unroll
    for (int j = 0; j < 5; j++) {
#pragma unroll
      for (int l = 0; l < 5; l++) {
        v[(i * 5 + j) * 5 + l] =
            tile[threadIdx.z + i][threadIdx.y + j][threadIdx.x + l];
      }
    }
  }
  float center = tile[threadIdx.z + 2][threadIdx.y + 2][threadIdx.x + 2];
  v[125] = __builtin_inff();
  v[126] = __builtin_inff();
  v[127] = __builtin_inff();
  float med = median125(v);
  float dlt = med - center;
  double c = (w < W && h < H && d < D) ? (double)dlt * (double)dlt : 0.0;
  double bs = block_reduce_sum(c, sh);
  if (tid == 0) {
    part[blockIdx.x + 6 * (blockIdx.y + 24 * blockIdx.z)] = bs;
  }
}

// ---------- stage 4: reduce partials, finalize 6 scalars ----------
// P: div partials (4 arrays of NDIVBLK), then 7 arrays of NMEDBLK.

__global__ __launch_bounds__(256) void finalize_kernel(
    const double* __restrict__ P, float* __restrict__ out) {
  __shared__ double sh[4];
  __shared__ double res[11];
  int tid = threadIdx.x;
  for (int q = 0; q < 11; q++) {
    const double* base =
        (q < 4) ? (P + q * NDIVBLK) : (P + 4 * NDIVBLK + (q - 4) * NMEDBLK);
    int cnt = (q < 4) ? NDIVBLK : NMEDBLK;
    double s = 0.0;
    for (int i = tid; i < cnt; i += 256) s += base[i];
#pragma unroll
    for (int off = 32; off > 0; off >>= 1) s += __shfl_down(s, off, 64);
    if ((tid & 63) == 0) sh[tid >> 6] = s;
    __syncthreads();
    if (tid == 0) res[q] = sh[0] + sh[1] + sh[2] + sh[3];
    __syncthreads();
  }
  if (tid == 0) {
    const double Nd = 95.0 * 95.0 * 95.0;
    const double Nj = 96.0 * 95.0 * 95.0;
    const double Nv = 96.0 * 96.0 * 96.0;
    double mp = res[0] / Nd;
    double mt = res[2] / Nd;
    out[0] = (float)mp;
    out[1] = (float)(res[1] / Nd - mp * mp);
    out[2] = (float)mt;
    out[3] = (float)(res[3] / Nd - mt * mt);
    out[4] = (float)((res[4] + res[5] + res[6]) / Nj);
    out[5] = (float)((res[7] + res[8] + res[9] + res[10]) / Nv);
  }
}

// ---------- launcher ----------

extern "C" void kernel_launch(void* const* d_in, const int* in_sizes, int n_in,
                              void* d_out, int out_size, void* d_ws,
                              size_t ws_size, hipStream_t stream) {
  (void)in_sizes;
  (void)n_in;
  (void)out_size;
  (void)ws_size;
  const float* pred_b = (const float*)d_in[0];
  const float* pred_z = (const float*)d_in[1];
  const float* targets = (const float*)d_in[2];
  float* out = (float*)d_out;

  double* P = (double*)d_ws;                     // 4*NDIVBLK + 7*NMEDBLK doubles
  size_t pdoubles = 4 * NDIVBLK + 7 * NMEDBLK;   // 37592 -> ~300 KB
  float* bxm = (float*)(P + pdoubles);
  float* bym = bxm + V96;

  const float* bzt = targets + 2 * V96;
  const float* bzp = pred_b + 2 * V96;

  prep_mask_kernel<<<dim3((V96 + 255) / 256), dim3(256), 0, stream>>>(
      pred_b, targets, bxm, bym);

  div_kernel<<<dim3(NDIVBLK), dim3(256), 0, stream>>>(
      pred_b, pred_b + V96, bzt, pred_z, P + 0 * NDIVBLK, P + 1 * NDIVBLK);
  div_kernel<<<dim3(NDIVBLK), dim3(256), 0, stream>>>(
      bxm, bym, bzt, pred_z, P + 2 * NDIVBLK, P + 3 * NDIVBLK);

  double* M = P + 4 * NDIVBLK;
  dim3 blk(16, 4, 4);
  dim3 grd(6, 24, 24);
  med_kernel<1><<<grd, blk, 0, stream>>>(nullptr, bxm, bym, bzp, 96, 95, 95,
                                         M + 0 * NMEDBLK);
  med_kernel<2><<<grd, blk, 0, stream>>>(nullptr, bxm, bym, bzp, 95, 96, 95,
                                         M + 1 * NMEDBLK);
  med_kernel<3><<<grd, blk, 0, stream>>>(nullptr, bxm, bym, bzp, 95, 95, 96,
                                         M + 2 * NMEDBLK);
  med_kernel<0><<<grd, blk, 0, stream>>>(bxm, bxm, bym, bzp, 96, 96, 96,
                                         M + 3 * NMEDBLK);
  med_kernel<0><<<grd, blk, 0, stream>>>(bym, bxm, bym, bzp, 96, 96, 96,
                                         M + 4 * NMEDBLK);
  med_kernel<0><<<grd, blk, 0, stream>>>(pred_b, bxm, bym, bzp, 96, 96, 96,
                                         M + 5 * NMEDBLK);
  med_kernel<0><<<grd, blk, 0, stream>>>(pred_b + V96, bxm, bym, bzp, 96, 96,
                                         96, M + 6 * NMEDBLK);

  finalize_kernel<<<1, 256, 0, stream>>>(P, out);
}